// Round 9
// baseline (247.272 us; speedup 1.0000x reference)
//
#include <hip/hip_runtime.h>

// Problem constants
#define B_ 8
#define V_ 10000
#define E_ 160000
#define DIN 128
#define DOUT 128
#define M_ (B_*V_)          // 80000 rows
#define NINV (1.0f/80000.0f)
#define BN_EPS 1e-5f

// Workspace layout (4-byte units):
#define WS_COUNTS  0            // V_            (zeroed)
#define WS_SUM     10000        // 128           (zeroed)
#define WS_SUMSQ   10128        // 128           (zeroed)
#define WS_ROWPTR  10512        // V_+1
#define WS_CURSOR  20513        // V_
#define WS_SSRC    30513        // E_      -> ends 190513
#define WS_EAS     190520       // E_*8    -> ends 1470520 (32B aligned)
#define WS_S       1470520      // M_      -> ends 1550520
#define WS_WPK     1550520      // 16384 = 32768 f16 (16B aligned)
#define WS_XH      1566904      // 5,120,000 units = 10.24M f16
#define WS_AH      6686904      // 5,120,000 units -> ends 11,806,904 (47.2MB)
#define WS_ZERO_UNITS 10256     // counts + gsum + gsumsq

typedef __attribute__((ext_vector_type(2))) _Float16 half2_t;
typedef __attribute__((ext_vector_type(4))) _Float16 half4_t;
typedef __attribute__((ext_vector_type(8))) _Float16 half8_t;
typedef __attribute__((ext_vector_type(4))) float f32x4;

__device__ inline half2_t i2h(unsigned i) {
    half2_t h; __builtin_memcpy(&h, &i, 4); return h;
}
__device__ inline unsigned h2i(half2_t h) {
    unsigned i; __builtin_memcpy(&i, &h, 4); return i;
}

// ---------------------------------------------------------------------------
// 1) fused prep: X->f16 row-major (blocks 0..9999)
//              + W fragment-major f16 pack (blocks 10000..10015)
//              + dst histogram (blocks 10016..10640)
// ---------------------------------------------------------------------------
__global__ __launch_bounds__(256) void prep_kernel(
    const float* __restrict__ X, _Float16* __restrict__ Xh,
    const float* __restrict__ Wself, const float* __restrict__ Wnode,
    _Float16* __restrict__ Wpk,
    const int* __restrict__ EI, int* __restrict__ counts)
{
    const int blk = blockIdx.x;
    const int t = threadIdx.x;
    if (blk < 10000) {
        int idx = blk * 256 + t;                 // over M_*DIN/4
        float4 v = ((const float4*)X)[idx];
        half4_t o = { (_Float16)v.x, (_Float16)v.y, (_Float16)v.z, (_Float16)v.w };
        ((half4_t*)Xh)[idx] = o;
    } else if (blk < 10016) {
        int g = (blk - 10000) * 256 + t;         // 0..4095
        int pair = g >> 6;                       // (ks,nt)
        int lane = g & 63;
        int ks = pair >> 3;
        int nt = pair & 7;
        int o = nt * 16 + (lane & 15);
        int k = ks * 32 + (lane >> 4) * 8;
        const float* wsrc = (k < 128) ? (Wself + o * 128 + k)
                                      : (Wnode + o * 128 + (k - 128));
        _Float16* dst = Wpk + ((size_t)pair * 64 + lane) * 8;
#pragma unroll
        for (int j = 0; j < 8; ++j) dst[j] = (_Float16)wsrc[j];
    } else {
        int e = (blk - 10016) * 256 + t;
        if (e < E_) atomicAdd(&counts[EI[2 * e + 1]], 1);
    }
}

// ---------------------------------------------------------------------------
// 2) exclusive prefix sum over counts -> row_ptr, cursor (single block)
// ---------------------------------------------------------------------------
__global__ __launch_bounds__(256) void scan_kernel(
    const int* __restrict__ counts, int* __restrict__ row_ptr,
    int* __restrict__ cursor)
{
    __shared__ int psum[256];
    const int t = threadIdx.x;
    const int base = t * 40;              // 256*40 = 10240 >= V_
    int local[40];
    int s = 0;
#pragma unroll
    for (int i = 0; i < 40; ++i) {
        int idx = base + i;
        int c = (idx < V_) ? counts[idx] : 0;
        local[i] = s;
        s += c;
    }
    psum[t] = s;
    __syncthreads();
    for (int off = 1; off < 256; off <<= 1) {
        int v = (t >= off) ? psum[t - off] : 0;
        __syncthreads();
        psum[t] += v;
        __syncthreads();
    }
    int excl = (t == 0) ? 0 : psum[t - 1];
#pragma unroll
    for (int i = 0; i < 40; ++i) {
        int idx = base + i;
        if (idx < V_) {
            int rp = excl + local[i];
            row_ptr[idx] = rp;
            cursor[idx] = rp;
        }
    }
    if (t == 255) row_ptr[V_] = psum[255];
}

// ---------------------------------------------------------------------------
// 3) scatter edges into dst-sorted buckets; also pre-sort edge_attr for all
//    8 batches into bucket order: EAs[p][b]
// ---------------------------------------------------------------------------
__global__ __launch_bounds__(256) void bucket_kernel(
    const int* __restrict__ EI, const float* __restrict__ EA,
    int* __restrict__ cursor, int* __restrict__ ssrc,
    float* __restrict__ EAs)
{
    int e = blockIdx.x * 256 + threadIdx.x;
    if (e < E_) {
        int src = EI[2 * e];
        int dst = EI[2 * e + 1];
        int p = atomicAdd(&cursor[dst], 1);
        ssrc[p] = src;
        float4 v0, v1;
        v0.x = EA[0 * E_ + e]; v0.y = EA[1 * E_ + e];
        v0.z = EA[2 * E_ + e]; v0.w = EA[3 * E_ + e];
        v1.x = EA[4 * E_ + e]; v1.y = EA[5 * E_ + e];
        v1.z = EA[6 * E_ + e]; v1.w = EA[7 * E_ + e];
        *(float4*)(EAs + (size_t)p * 8) = v0;
        *(float4*)(EAs + (size_t)p * 8 + 4) = v1;
    }
}

// ---------------------------------------------------------------------------
// 4) gather-reduce, f16, 2 edges per wave-step, batch-per-XCD swizzled:
//    Ah[b,d,:] = f16( sum_{e:dst=d} Xh[b,src,:] ); S[b,d] = sum ea
// ---------------------------------------------------------------------------
__global__ __launch_bounds__(256) void gather_kernel(
    const _Float16* __restrict__ Xh, const float* __restrict__ EAs,
    const int* __restrict__ row_ptr, const int* __restrict__ ssrc,
    _Float16* __restrict__ Ah, float* __restrict__ S)
{
    const int b = blockIdx.x & 7;             // batch -> XCD
    const int dblk = blockIdx.x >> 3;         // 0..2499
    const int w = threadIdx.x >> 6;           // 4 waves/block
    const int lane = threadIdx.x & 63;
    const int half = lane >> 5;               // which edge of the pair
    const int sl = lane & 31;                 // element group: sl*4 .. sl*4+3
    const int d = dblk * 4 + w;
    const int wid = b * V_ + d;
    const int k0 = row_ptr[d];
    const int k1 = row_ptr[d + 1];
    const _Float16* Xb = Xh + (size_t)b * V_ * DIN + sl * 4;
    half2_t a0 = (half2_t)0, a1 = (half2_t)0;
    float ea = 0.0f;
    for (int kb = k0; kb < k1; kb += 64) {
        int cnt = min(64, k1 - kb);
        int msrc = 0;
        if (lane < cnt) {
            msrc = ssrc[kb + lane];
            ea += EAs[(size_t)(kb + lane) * 8 + b];
        }
        int j = 0;
        for (; j + 8 <= cnt; j += 8) {
#pragma unroll
            for (int u = 0; u < 4; ++u) {
                int s = __shfl(msrc, j + u * 2 + half);
                uint2 v = *(const uint2*)(Xb + (size_t)s * DIN);
                a0 += i2h(v.x);
                a1 += i2h(v.y);
            }
        }
        for (; j + 2 <= cnt; j += 2) {
            int s = __shfl(msrc, j + half);
            uint2 v = *(const uint2*)(Xb + (size_t)s * DIN);
            a0 += i2h(v.x);
            a1 += i2h(v.y);
        }
        if (j < cnt) {
            int s = __shfl(msrc, j);
            if (half == 0) {
                uint2 v = *(const uint2*)(Xb + (size_t)s * DIN);
                a0 += i2h(v.x);
                a1 += i2h(v.y);
            }
        }
    }
    // combine the two edge-parity halves (lane <- lane+32)
    unsigned c0 = __shfl_down(h2i(a0), 32);
    unsigned c1 = __shfl_down(h2i(a1), 32);
    a0 += i2h(c0);
    a1 += i2h(c1);
    // edge_attr wave reduction
    for (int off = 32; off; off >>= 1) ea += __shfl_down(ea, off);
    if (lane == 0) S[wid] = ea;
    if (half == 0) {
        uint2 o;
        o.x = h2i(a0);
        o.y = h2i(a1);
        *(uint2*)(Ah + (size_t)wid * DIN + sl * 4) = o;
    }
}

// ---------------------------------------------------------------------------
// 5) MFMA GEMM (f16) + fused BN stats.
//    128-thread block = 2 waves; wave = 32 rows (2 m-tiles) x 128 cols.
//    1250 blocks of 2 waves -> whole grid co-resident (~10 waves/CU at
//    ~88 VGPR), with R6's 2x W-fragment amortization per wave.
// ---------------------------------------------------------------------------
__global__ __launch_bounds__(128) void mfma_gemm_kernel(
    const _Float16* __restrict__ Xh, const _Float16* __restrict__ Ah,
    const _Float16* __restrict__ Wpk, const float* __restrict__ S,
    const float* __restrict__ bself, const float* __restrict__ wedge,
    float* __restrict__ H, float* __restrict__ gsum, float* __restrict__ gsumsq)
{
    __shared__ float cs[128];
    __shared__ float css[128];
    const int t = threadIdx.x;
    const int wave = t >> 6;              // 0..1
    const int lane = t & 63;
    const int quad = lane >> 4;
    const int ln = lane & 15;
    const int rowbase = blockIdx.x * 64 + wave * 32;
    const int m0 = rowbase + ln;          // m-tile 0 A-frag row
    const int m1 = rowbase + 16 + ln;     // m-tile 1 A-frag row

    cs[t] = 0.0f; css[t] = 0.0f;          // 128 threads cover all 128 chans

    f32x4 acc[2][8];
#pragma unroll
    for (int mt = 0; mt < 2; ++mt)
#pragma unroll
        for (int nt = 0; nt < 8; ++nt) acc[mt][nt] = (f32x4){0.f, 0.f, 0.f, 0.f};

    const _Float16* X0 = Xh + (size_t)m0 * DIN + quad * 8;
    const _Float16* X1 = Xh + (size_t)m1 * DIN + quad * 8;
    const _Float16* A0 = Ah + (size_t)m0 * DIN + quad * 8;
    const _Float16* A1 = Ah + (size_t)m1 * DIN + quad * 8;
    const _Float16* Wl = Wpk + lane * 8;

#pragma unroll
    for (int ks = 0; ks < 8; ++ks) {
        half8_t af0, af1;
        if (ks < 4) {
            af0 = *(const half8_t*)(X0 + ks * 32);
            af1 = *(const half8_t*)(X1 + ks * 32);
        } else {
            af0 = *(const half8_t*)(A0 + (ks - 4) * 32);
            af1 = *(const half8_t*)(A1 + (ks - 4) * 32);
        }
#pragma unroll
        for (int nt = 0; nt < 8; ++nt) {
            half8_t bfr = *(const half8_t*)(Wl + (size_t)(ks * 8 + nt) * 512);
            acc[0][nt] = __builtin_amdgcn_mfma_f32_16x16x32_f16(af0, bfr, acc[0][nt], 0, 0, 0);
            acc[1][nt] = __builtin_amdgcn_mfma_f32_16x16x32_f16(af1, bfr, acc[1][nt], 0, 0, 0);
        }
    }

    // epilogue: bias + S*w_edge, store H, accumulate stats
    float bs[8], we[8];
#pragma unroll
    for (int nt = 0; nt < 8; ++nt) {
        int c = nt * 16 + ln;
        bs[nt] = bself[c];
        we[nt] = wedge[c];
    }
    float psum[8], psq[8];
#pragma unroll
    for (int nt = 0; nt < 8; ++nt) { psum[nt] = 0.0f; psq[nt] = 0.0f; }

#pragma unroll
    for (int mt = 0; mt < 2; ++mt) {
        const int rbase = rowbase + mt * 16 + quad * 4;   // C/D: col=ln, row=quad*4+r
        float sv[4];
#pragma unroll
        for (int r = 0; r < 4; ++r) sv[r] = S[rbase + r];
#pragma unroll
        for (int r = 0; r < 4; ++r) {
            float* Hr = H + (size_t)(rbase + r) * DOUT + ln;
#pragma unroll
            for (int nt = 0; nt < 8; ++nt) {
                float h = acc[mt][nt][r] + bs[nt] + sv[r] * we[nt];
                Hr[nt * 16] = h;
                psum[nt] += h;
                psq[nt] += h * h;
            }
        }
    }
    // reduce across quads (lanes ln, ln+16, ln+32, ln+48)
#pragma unroll
    for (int nt = 0; nt < 8; ++nt) {
        psum[nt] += __shfl_down(psum[nt], 32);
        psum[nt] += __shfl_down(psum[nt], 16);
        psq[nt] += __shfl_down(psq[nt], 32);
        psq[nt] += __shfl_down(psq[nt], 16);
    }
    __syncthreads();   // cs/css zeros visible
    if (lane < 16) {
#pragma unroll
        for (int nt = 0; nt < 8; ++nt) {
            atomicAdd(&cs[nt * 16 + ln], psum[nt]);
            atomicAdd(&css[nt * 16 + ln], psq[nt]);
        }
    }
    __syncthreads();
    atomicAdd(&gsum[t], cs[t]);
    atomicAdd(&gsumsq[t], css[t]);
}

// ---------------------------------------------------------------------------
// 6) normalize + ReLU in place (finalize fused)
// ---------------------------------------------------------------------------
__global__ __launch_bounds__(256) void norm_relu_kernel(
    float* __restrict__ H, const float* __restrict__ gsum,
    const float* __restrict__ gsumsq, const float* __restrict__ gamma,
    const float* __restrict__ beta)
{
    int idx = blockIdx.x * 256 + threadIdx.x;   // over M_*128/4 float4s
    int o4 = (idx & 31) * 4;
    float4 s = *(const float4*)(gsum + o4);
    float4 q = *(const float4*)(gsumsq + o4);
    float4 g = *(const float4*)(gamma + o4);
    float4 bt = *(const float4*)(beta + o4);
    float4 sc, sh;
    {
        float m0 = s.x * NINV, m1 = s.y * NINV, m2 = s.z * NINV, m3 = s.w * NINV;
        float r0 = rsqrtf(q.x * NINV - m0 * m0 + BN_EPS);
        float r1 = rsqrtf(q.y * NINV - m1 * m1 + BN_EPS);
        float r2 = rsqrtf(q.z * NINV - m2 * m2 + BN_EPS);
        float r3 = rsqrtf(q.w * NINV - m3 * m3 + BN_EPS);
        sc.x = g.x * r0; sc.y = g.y * r1; sc.z = g.z * r2; sc.w = g.w * r3;
        sh.x = bt.x - m0 * sc.x; sh.y = bt.y - m1 * sc.y;
        sh.z = bt.z - m2 * sc.z; sh.w = bt.w - m3 * sc.w;
    }
    float4 h = ((const float4*)H)[idx];
    h.x = fmaxf(h.x * sc.x + sh.x, 0.0f);
    h.y = fmaxf(h.y * sc.y + sh.y, 0.0f);
    h.z = fmaxf(h.z * sc.z + sh.z, 0.0f);
    h.w = fmaxf(h.w * sc.w + sh.w, 0.0f);
    ((float4*)H)[idx] = h;
}

// ---------------------------------------------------------------------------
extern "C" void kernel_launch(void* const* d_in, const int* in_sizes, int n_in,
                              void* d_out, int out_size, void* d_ws, size_t ws_size,
                              hipStream_t stream)
{
    const float* X      = (const float*)d_in[0];
    const float* EA     = (const float*)d_in[1];
    const float* Wnode  = (const float*)d_in[2];
    const float* Wedge  = (const float*)d_in[3];
    const float* Wself  = (const float*)d_in[4];
    const float* bself  = (const float*)d_in[5];
    const float* gamma  = (const float*)d_in[6];
    const float* beta   = (const float*)d_in[7];
    const int*   EI     = (const int*)d_in[8];

    int*   wsI    = (int*)d_ws;
    float* wsF    = (float*)d_ws;
    int*   counts = wsI + WS_COUNTS;
    float* gsum   = wsF + WS_SUM;
    float* gsumsq = wsF + WS_SUMSQ;
    int*   rowptr = wsI + WS_ROWPTR;
    int*   cursor = wsI + WS_CURSOR;
    int*   ssrc   = wsI + WS_SSRC;
    float* EAs    = wsF + WS_EAS;
    float* S      = wsF + WS_S;
    _Float16* Wpk = (_Float16*)(wsI + WS_WPK);
    _Float16* Xh  = (_Float16*)(wsI + WS_XH);
    _Float16* Ah  = (_Float16*)(wsI + WS_AH);
    float* H      = (float*)d_out;

    hipMemsetAsync(d_ws, 0, (size_t)WS_ZERO_UNITS * 4, stream);

    // fused prep: xcvt (10000 blocks) + W pack (16) + hist (625)
    prep_kernel<<<10641, 256, 0, stream>>>(X, Xh, Wself, Wnode, Wpk, EI, counts);
    scan_kernel<<<1, 256, 0, stream>>>(counts, rowptr, cursor);
    bucket_kernel<<<(E_ + 255) / 256, 256, 0, stream>>>(EI, EA, cursor, ssrc, EAs);

    // gather-reduce -> Ah, S  (batch-per-XCD swizzle, 2 edges/wave-step)
    gather_kernel<<<M_ / 4, 256, 0, stream>>>(Xh, EAs, rowptr, ssrc, Ah, S);

    // MFMA GEMM + stats -> H, gsum, gsumsq (2-wave blocks, 64 rows each)
    mfma_gemm_kernel<<<M_ / 64, 128, 0, stream>>>(Xh, Ah, Wpk, S, bself, Wedge,
                                                  H, gsum, gsumsq);

    // normalize + relu (finalize fused)
    norm_relu_kernel<<<(M_ * DOUT / 4) / 256, 256, 0, stream>>>(H, gsum, gsumsq,
                                                                gamma, beta);
}

// Round 10
// 226.337 us; speedup vs baseline: 1.0925x; 1.0925x over previous
//
#include <hip/hip_runtime.h>

// Problem constants
#define B_ 8
#define V_ 10000
#define E_ 160000
#define DIN 128
#define DOUT 128
#define M_ (B_*V_)          // 80000 rows
#define NINV (1.0f/80000.0f)
#define BN_EPS 1e-5f

#define GEMM_BLOCKS 625     // 128 rows per block

// Workspace layout (4-byte units):
#define WS_COUNTS  0            // V_            (zeroed)
#define WS_SUM     10000        // 128
#define WS_SUMSQ   10128        // 128
#define WS_ROWPTR  10512        // V_+1
#define WS_CURSOR  20513        // V_
#define WS_SSRC    30513        // E_      -> ends 190513
#define WS_EAS     190520       // E_*8    -> ends 1470520 (32B aligned)
#define WS_S       1470520      // M_      -> ends 1550520
#define WS_WPK     1550520      // 16384 = 32768 f16 (16B aligned)
#define WS_XH      1566904      // 5,120,000 units = 10.24M f16
#define WS_AH      6686904      // 5,120,000 units -> ends 11,806,904
#define WS_PART    11806904     // 625*256 = 160,000 -> ends 11,966,904 (47.9MB)
#define WS_ZERO_UNITS 10000     // counts only

typedef __attribute__((ext_vector_type(2))) _Float16 half2_t;
typedef __attribute__((ext_vector_type(4))) _Float16 half4_t;
typedef __attribute__((ext_vector_type(8))) _Float16 half8_t;
typedef __attribute__((ext_vector_type(4))) float f32x4;

__device__ inline half2_t i2h(unsigned i) {
    half2_t h; __builtin_memcpy(&h, &i, 4); return h;
}
__device__ inline unsigned h2i(half2_t h) {
    unsigned i; __builtin_memcpy(&i, &h, 4); return i;
}

// ---------------------------------------------------------------------------
// 1) fused prep: X->f16 row-major (blocks 0..9999)
//              + W fragment-major f16 pack (blocks 10000..10015)
//              + dst histogram (blocks 10016..10640)
// ---------------------------------------------------------------------------
__global__ __launch_bounds__(256) void prep_kernel(
    const float* __restrict__ X, _Float16* __restrict__ Xh,
    const float* __restrict__ Wself, const float* __restrict__ Wnode,
    _Float16* __restrict__ Wpk,
    const int* __restrict__ EI, int* __restrict__ counts)
{
    const int blk = blockIdx.x;
    const int t = threadIdx.x;
    if (blk < 10000) {
        int idx = blk * 256 + t;                 // over M_*DIN/4
        float4 v = ((const float4*)X)[idx];
        half4_t o = { (_Float16)v.x, (_Float16)v.y, (_Float16)v.z, (_Float16)v.w };
        ((half4_t*)Xh)[idx] = o;
    } else if (blk < 10016) {
        int g = (blk - 10000) * 256 + t;         // 0..4095
        int pair = g >> 6;                       // (ks,nt)
        int lane = g & 63;
        int ks = pair >> 3;
        int nt = pair & 7;
        int o = nt * 16 + (lane & 15);
        int k = ks * 32 + (lane >> 4) * 8;
        const float* wsrc = (k < 128) ? (Wself + o * 128 + k)
                                      : (Wnode + o * 128 + (k - 128));
        _Float16* dst = Wpk + ((size_t)pair * 64 + lane) * 8;
#pragma unroll
        for (int j = 0; j < 8; ++j) dst[j] = (_Float16)wsrc[j];
    } else {
        int e = (blk - 10016) * 256 + t;
        if (e < E_) atomicAdd(&counts[EI[2 * e + 1]], 1);
    }
}

// ---------------------------------------------------------------------------
// 2) exclusive prefix sum over counts -> row_ptr, cursor (single block)
// ---------------------------------------------------------------------------
__global__ __launch_bounds__(256) void scan_kernel(
    const int* __restrict__ counts, int* __restrict__ row_ptr,
    int* __restrict__ cursor)
{
    __shared__ int psum[256];
    const int t = threadIdx.x;
    const int base = t * 40;              // 256*40 = 10240 >= V_
    int local[40];
    int s = 0;
#pragma unroll
    for (int i = 0; i < 40; ++i) {
        int idx = base + i;
        int c = (idx < V_) ? counts[idx] : 0;
        local[i] = s;
        s += c;
    }
    psum[t] = s;
    __syncthreads();
    for (int off = 1; off < 256; off <<= 1) {
        int v = (t >= off) ? psum[t - off] : 0;
        __syncthreads();
        psum[t] += v;
        __syncthreads();
    }
    int excl = (t == 0) ? 0 : psum[t - 1];
#pragma unroll
    for (int i = 0; i < 40; ++i) {
        int idx = base + i;
        if (idx < V_) {
            int rp = excl + local[i];
            row_ptr[idx] = rp;
            cursor[idx] = rp;
        }
    }
    if (t == 255) row_ptr[V_] = psum[255];
}

// ---------------------------------------------------------------------------
// 3) scatter edges into dst-sorted buckets; also pre-sort edge_attr for all
//    8 batches into bucket order: EAs[p][b]
// ---------------------------------------------------------------------------
__global__ __launch_bounds__(256) void bucket_kernel(
    const int* __restrict__ EI, const float* __restrict__ EA,
    int* __restrict__ cursor, int* __restrict__ ssrc,
    float* __restrict__ EAs)
{
    int e = blockIdx.x * 256 + threadIdx.x;
    if (e < E_) {
        int src = EI[2 * e];
        int dst = EI[2 * e + 1];
        int p = atomicAdd(&cursor[dst], 1);
        ssrc[p] = src;
        float4 v0, v1;
        v0.x = EA[0 * E_ + e]; v0.y = EA[1 * E_ + e];
        v0.z = EA[2 * E_ + e]; v0.w = EA[3 * E_ + e];
        v1.x = EA[4 * E_ + e]; v1.y = EA[5 * E_ + e];
        v1.z = EA[6 * E_ + e]; v1.w = EA[7 * E_ + e];
        *(float4*)(EAs + (size_t)p * 8) = v0;
        *(float4*)(EAs + (size_t)p * 8 + 4) = v1;
    }
}

// ---------------------------------------------------------------------------
// 4) gather-reduce, f16, 2 edges per wave-step, batch-per-XCD swizzled:
//    Ah[b,d,:] = f16( sum_{e:dst=d} Xh[b,src,:] ); S[b,d] = sum ea
// ---------------------------------------------------------------------------
__global__ __launch_bounds__(256) void gather_kernel(
    const _Float16* __restrict__ Xh, const float* __restrict__ EAs,
    const int* __restrict__ row_ptr, const int* __restrict__ ssrc,
    _Float16* __restrict__ Ah, float* __restrict__ S)
{
    const int b = blockIdx.x & 7;             // batch -> XCD
    const int dblk = blockIdx.x >> 3;         // 0..2499
    const int w = threadIdx.x >> 6;           // 4 waves/block
    const int lane = threadIdx.x & 63;
    const int half = lane >> 5;               // which edge of the pair
    const int sl = lane & 31;                 // element group: sl*4 .. sl*4+3
    const int d = dblk * 4 + w;
    const int wid = b * V_ + d;
    const int k0 = row_ptr[d];
    const int k1 = row_ptr[d + 1];
    const _Float16* Xb = Xh + (size_t)b * V_ * DIN + sl * 4;
    half2_t a0 = (half2_t)0, a1 = (half2_t)0;
    float ea = 0.0f;
    for (int kb = k0; kb < k1; kb += 64) {
        int cnt = min(64, k1 - kb);
        int msrc = 0;
        if (lane < cnt) {
            msrc = ssrc[kb + lane];
            ea += EAs[(size_t)(kb + lane) * 8 + b];
        }
        int j = 0;
        for (; j + 8 <= cnt; j += 8) {
#pragma unroll
            for (int u = 0; u < 4; ++u) {
                int s = __shfl(msrc, j + u * 2 + half);
                uint2 v = *(const uint2*)(Xb + (size_t)s * DIN);
                a0 += i2h(v.x);
                a1 += i2h(v.y);
            }
        }
        for (; j + 2 <= cnt; j += 2) {
            int s = __shfl(msrc, j + half);
            uint2 v = *(const uint2*)(Xb + (size_t)s * DIN);
            a0 += i2h(v.x);
            a1 += i2h(v.y);
        }
        if (j < cnt) {
            int s = __shfl(msrc, j);
            if (half == 0) {
                uint2 v = *(const uint2*)(Xb + (size_t)s * DIN);
                a0 += i2h(v.x);
                a1 += i2h(v.y);
            }
        }
    }
    // combine the two edge-parity halves (lane <- lane+32)
    unsigned c0 = __shfl_down(h2i(a0), 32);
    unsigned c1 = __shfl_down(h2i(a1), 32);
    a0 += i2h(c0);
    a1 += i2h(c1);
    // edge_attr wave reduction
    for (int off = 32; off; off >>= 1) ea += __shfl_down(ea, off);
    if (lane == 0) S[wid] = ea;
    if (half == 0) {
        uint2 o;
        o.x = h2i(a0);
        o.y = h2i(a1);
        *(uint2*)(Ah + (size_t)wid * DIN + sl * 4) = o;
    }
}

// ---------------------------------------------------------------------------
// 5) MFMA GEMM (f16) + per-block BN partials (NO global atomics).
//    256 threads = 4 waves; wave = 32 rows (2 m-tiles) x 128 cols;
//    128 rows/block, 625 blocks (R6's measured-best geometry).
//    Block partials -> Partials[bid][256] via plain coalesced stores.
// ---------------------------------------------------------------------------
__global__ __launch_bounds__(256) void mfma_gemm_kernel(
    const _Float16* __restrict__ Xh, const _Float16* __restrict__ Ah,
    const _Float16* __restrict__ Wpk, const float* __restrict__ S,
    const float* __restrict__ bself, const float* __restrict__ wedge,
    float* __restrict__ H, float* __restrict__ Partials)
{
    __shared__ float cs[128];
    __shared__ float css[128];
    const int t = threadIdx.x;
    const int wave = t >> 6;
    const int lane = t & 63;
    const int quad = lane >> 4;
    const int ln = lane & 15;
    const int rowbase = blockIdx.x * 128 + wave * 32;
    const int m0 = rowbase + ln;          // m-tile 0 A-frag row
    const int m1 = rowbase + 16 + ln;     // m-tile 1 A-frag row

    if (t < 128) { cs[t] = 0.0f; css[t] = 0.0f; }

    f32x4 acc[2][8];
#pragma unroll
    for (int mt = 0; mt < 2; ++mt)
#pragma unroll
        for (int nt = 0; nt < 8; ++nt) acc[mt][nt] = (f32x4){0.f, 0.f, 0.f, 0.f};

    const _Float16* X0 = Xh + (size_t)m0 * DIN + quad * 8;
    const _Float16* X1 = Xh + (size_t)m1 * DIN + quad * 8;
    const _Float16* A0 = Ah + (size_t)m0 * DIN + quad * 8;
    const _Float16* A1 = Ah + (size_t)m1 * DIN + quad * 8;
    const _Float16* Wl = Wpk + lane * 8;

#pragma unroll
    for (int ks = 0; ks < 8; ++ks) {
        half8_t af0, af1;
        if (ks < 4) {
            af0 = *(const half8_t*)(X0 + ks * 32);
            af1 = *(const half8_t*)(X1 + ks * 32);
        } else {
            af0 = *(const half8_t*)(A0 + (ks - 4) * 32);
            af1 = *(const half8_t*)(A1 + (ks - 4) * 32);
        }
#pragma unroll
        for (int nt = 0; nt < 8; ++nt) {
            half8_t bfr = *(const half8_t*)(Wl + (size_t)(ks * 8 + nt) * 512);
            acc[0][nt] = __builtin_amdgcn_mfma_f32_16x16x32_f16(af0, bfr, acc[0][nt], 0, 0, 0);
            acc[1][nt] = __builtin_amdgcn_mfma_f32_16x16x32_f16(af1, bfr, acc[1][nt], 0, 0, 0);
        }
    }

    // epilogue: bias + S*w_edge, store H, accumulate per-block stats
    float bs[8], we[8];
#pragma unroll
    for (int nt = 0; nt < 8; ++nt) {
        int c = nt * 16 + ln;
        bs[nt] = bself[c];
        we[nt] = wedge[c];
    }
    float psum[8], psq[8];
#pragma unroll
    for (int nt = 0; nt < 8; ++nt) { psum[nt] = 0.0f; psq[nt] = 0.0f; }

#pragma unroll
    for (int mt = 0; mt < 2; ++mt) {
        const int rbase = rowbase + mt * 16 + quad * 4;   // C/D: col=ln, row=quad*4+r
        float sv[4];
#pragma unroll
        for (int r = 0; r < 4; ++r) sv[r] = S[rbase + r];
#pragma unroll
        for (int r = 0; r < 4; ++r) {
            float* Hr = H + (size_t)(rbase + r) * DOUT + ln;
#pragma unroll
            for (int nt = 0; nt < 8; ++nt) {
                float h = acc[mt][nt][r] + bs[nt] + sv[r] * we[nt];
                Hr[nt * 16] = h;
                psum[nt] += h;
                psq[nt] += h * h;
            }
        }
    }
    // reduce across quads (lanes ln, ln+16, ln+32, ln+48)
#pragma unroll
    for (int nt = 0; nt < 8; ++nt) {
        psum[nt] += __shfl_down(psum[nt], 32);
        psum[nt] += __shfl_down(psum[nt], 16);
        psq[nt] += __shfl_down(psq[nt], 32);
        psq[nt] += __shfl_down(psq[nt], 16);
    }
    __syncthreads();   // cs/css zeros visible
    if (lane < 16) {
#pragma unroll
        for (int nt = 0; nt < 8; ++nt) {
            atomicAdd(&cs[nt * 16 + ln], psum[nt]);
            atomicAdd(&css[nt * 16 + ln], psq[nt]);
        }
    }
    __syncthreads();
    // plain coalesced store of the block's 256 partials (no global atomics)
    Partials[(size_t)blockIdx.x * 256 + t] = (t < 128) ? cs[t] : css[t - 128];
}

// ---------------------------------------------------------------------------
// 6) reduce 625 block-partials -> gsum / gsumsq. 256 blocks x 64 threads;
//    block c handles channel-slot c (0..127 = sum, 128..255 = sumsq).
// ---------------------------------------------------------------------------
__global__ __launch_bounds__(64) void reduce_stats_kernel(
    const float* __restrict__ Partials, float* __restrict__ gsum,
    float* __restrict__ gsumsq)
{
    const int c = blockIdx.x;       // 0..255
    const int t = threadIdx.x;      // 0..63
    float acc = 0.0f;
    for (int p = t; p < GEMM_BLOCKS; p += 64)
        acc += Partials[(size_t)p * 256 + c];
    for (int off = 32; off; off >>= 1) acc += __shfl_down(acc, off);
    if (t == 0) {
        if (c < 128) gsum[c] = acc;
        else gsumsq[c - 128] = acc;
    }
}

// ---------------------------------------------------------------------------
// 7) normalize + ReLU in place (finalize fused)
// ---------------------------------------------------------------------------
__global__ __launch_bounds__(256) void norm_relu_kernel(
    float* __restrict__ H, const float* __restrict__ gsum,
    const float* __restrict__ gsumsq, const float* __restrict__ gamma,
    const float* __restrict__ beta)
{
    int idx = blockIdx.x * 256 + threadIdx.x;   // over M_*128/4 float4s
    int o4 = (idx & 31) * 4;
    float4 s = *(const float4*)(gsum + o4);
    float4 q = *(const float4*)(gsumsq + o4);
    float4 g = *(const float4*)(gamma + o4);
    float4 bt = *(const float4*)(beta + o4);
    float4 sc, sh;
    {
        float m0 = s.x * NINV, m1 = s.y * NINV, m2 = s.z * NINV, m3 = s.w * NINV;
        float r0 = rsqrtf(q.x * NINV - m0 * m0 + BN_EPS);
        float r1 = rsqrtf(q.y * NINV - m1 * m1 + BN_EPS);
        float r2 = rsqrtf(q.z * NINV - m2 * m2 + BN_EPS);
        float r3 = rsqrtf(q.w * NINV - m3 * m3 + BN_EPS);
        sc.x = g.x * r0; sc.y = g.y * r1; sc.z = g.z * r2; sc.w = g.w * r3;
        sh.x = bt.x - m0 * sc.x; sh.y = bt.y - m1 * sc.y;
        sh.z = bt.z - m2 * sc.z; sh.w = bt.w - m3 * sc.w;
    }
    float4 h = ((const float4*)H)[idx];
    h.x = fmaxf(h.x * sc.x + sh.x, 0.0f);
    h.y = fmaxf(h.y * sc.y + sh.y, 0.0f);
    h.z = fmaxf(h.z * sc.z + sh.z, 0.0f);
    h.w = fmaxf(h.w * sc.w + sh.w, 0.0f);
    ((float4*)H)[idx] = h;
}

// ---------------------------------------------------------------------------
extern "C" void kernel_launch(void* const* d_in, const int* in_sizes, int n_in,
                              void* d_out, int out_size, void* d_ws, size_t ws_size,
                              hipStream_t stream)
{
    const float* X      = (const float*)d_in[0];
    const float* EA     = (const float*)d_in[1];
    const float* Wnode  = (const float*)d_in[2];
    const float* Wedge  = (const float*)d_in[3];
    const float* Wself  = (const float*)d_in[4];
    const float* bself  = (const float*)d_in[5];
    const float* gamma  = (const float*)d_in[6];
    const float* beta   = (const float*)d_in[7];
    const int*   EI     = (const int*)d_in[8];

    int*   wsI    = (int*)d_ws;
    float* wsF    = (float*)d_ws;
    int*   counts = wsI + WS_COUNTS;
    float* gsum   = wsF + WS_SUM;
    float* gsumsq = wsF + WS_SUMSQ;
    int*   rowptr = wsI + WS_ROWPTR;
    int*   cursor = wsI + WS_CURSOR;
    int*   ssrc   = wsI + WS_SSRC;
    float* EAs    = wsF + WS_EAS;
    float* S      = wsF + WS_S;
    _Float16* Wpk = (_Float16*)(wsI + WS_WPK);
    _Float16* Xh  = (_Float16*)(wsI + WS_XH);
    _Float16* Ah  = (_Float16*)(wsI + WS_AH);
    float* Partials = wsF + WS_PART;
    float* H      = (float*)d_out;

    hipMemsetAsync(d_ws, 0, (size_t)WS_ZERO_UNITS * 4, stream);

    // fused prep: xcvt (10000 blocks) + W pack (16) + hist (625)
    prep_kernel<<<10641, 256, 0, stream>>>(X, Xh, Wself, Wnode, Wpk, EI, counts);
    scan_kernel<<<1, 256, 0, stream>>>(counts, rowptr, cursor);
    bucket_kernel<<<(E_ + 255) / 256, 256, 0, stream>>>(EI, EA, cursor, ssrc, EAs);

    // gather-reduce -> Ah, S  (batch-per-XCD swizzle, 2 edges/wave-step)
    gather_kernel<<<M_ / 4, 256, 0, stream>>>(Xh, EAs, rowptr, ssrc, Ah, S);

    // MFMA GEMM -> H + block partials (625 blocks, no global atomics)
    mfma_gemm_kernel<<<GEMM_BLOCKS, 256, 0, stream>>>(Xh, Ah, Wpk, S, bself,
                                                      Wedge, H, Partials);

    // partials -> gsum/gsumsq
    reduce_stats_kernel<<<256, 64, 0, stream>>>(Partials, gsum, gsumsq);

    // normalize + relu (finalize fused)
    norm_relu_kernel<<<(M_ * DOUT / 4) / 256, 256, 0, stream>>>(H, gsum, gsumsq,
                                                                gamma, beta);
}

// Round 11
// 221.640 us; speedup vs baseline: 1.1156x; 1.0212x over previous
//
#include <hip/hip_runtime.h>
#include <hip/hip_cooperative_groups.h>

namespace cg = cooperative_groups;

// Problem constants
#define B_ 8
#define V_ 10000
#define E_ 160000
#define DIN 128
#define DOUT 128
#define M_ (B_*V_)          // 80000 rows
#define NINV (1.0f/80000.0f)
#define BN_EPS 1e-5f

#define GEMM_BLOCKS 625     // 128 rows per block

// Workspace layout (4-byte units):
#define WS_COUNTS  0            // V_            (zeroed)
#define WS_SUM     10000        // 128
#define WS_SUMSQ   10128        // 128
#define WS_ROWPTR  10512        // V_+1
#define WS_CURSOR  20513        // V_
#define WS_SSRC    30513        // E_      -> ends 190513
#define WS_EAS     190520       // E_*8    -> ends 1470520 (32B aligned)
#define WS_S       1470520      // M_      -> ends 1550520
#define WS_WPK     1550520      // 16384 = 32768 f16 (16B aligned)
#define WS_XH      1566904      // 5,120,000 units = 10.24M f16
#define WS_AH      6686904      // 5,120,000 units -> ends 11,806,904
#define WS_PART    11806904     // 625*256 = 160,000 -> ends 11,966,904 (47.9MB)
#define WS_ZERO_UNITS 10000     // counts only

typedef __attribute__((ext_vector_type(2))) _Float16 half2_t;
typedef __attribute__((ext_vector_type(4))) _Float16 half4_t;
typedef __attribute__((ext_vector_type(8))) _Float16 half8_t;
typedef __attribute__((ext_vector_type(4))) float f32x4;

__device__ inline half2_t i2h(unsigned i) {
    half2_t h; __builtin_memcpy(&h, &i, 4); return h;
}
__device__ inline unsigned h2i(half2_t h) {
    unsigned i; __builtin_memcpy(&i, &h, 4); return i;
}

// ---------------------------------------------------------------------------
// 1) fused prep: X->f16 row-major (blocks 0..9999)
//              + W fragment-major f16 pack (blocks 10000..10015)
//              + dst histogram (blocks 10016..10640)
// ---------------------------------------------------------------------------
__global__ __launch_bounds__(256) void prep_kernel(
    const float* __restrict__ X, _Float16* __restrict__ Xh,
    const float* __restrict__ Wself, const float* __restrict__ Wnode,
    _Float16* __restrict__ Wpk,
    const int* __restrict__ EI, int* __restrict__ counts)
{
    const int blk = blockIdx.x;
    const int t = threadIdx.x;
    if (blk < 10000) {
        int idx = blk * 256 + t;                 // over M_*DIN/4
        float4 v = ((const float4*)X)[idx];
        half4_t o = { (_Float16)v.x, (_Float16)v.y, (_Float16)v.z, (_Float16)v.w };
        ((half4_t*)Xh)[idx] = o;
    } else if (blk < 10016) {
        int g = (blk - 10000) * 256 + t;         // 0..4095
        int pair = g >> 6;                       // (ks,nt)
        int lane = g & 63;
        int ks = pair >> 3;
        int nt = pair & 7;
        int o = nt * 16 + (lane & 15);
        int k = ks * 32 + (lane >> 4) * 8;
        const float* wsrc = (k < 128) ? (Wself + o * 128 + k)
                                      : (Wnode + o * 128 + (k - 128));
        _Float16* dst = Wpk + ((size_t)pair * 64 + lane) * 8;
#pragma unroll
        for (int j = 0; j < 8; ++j) dst[j] = (_Float16)wsrc[j];
    } else {
        int e = (blk - 10016) * 256 + t;
        if (e < E_) atomicAdd(&counts[EI[2 * e + 1]], 1);
    }
}

// ---------------------------------------------------------------------------
// 2) exclusive prefix sum over counts -> row_ptr, cursor (single block)
// ---------------------------------------------------------------------------
__global__ __launch_bounds__(256) void scan_kernel(
    const int* __restrict__ counts, int* __restrict__ row_ptr,
    int* __restrict__ cursor)
{
    __shared__ int psum[256];
    const int t = threadIdx.x;
    const int base = t * 40;              // 256*40 = 10240 >= V_
    int local[40];
    int s = 0;
#pragma unroll
    for (int i = 0; i < 40; ++i) {
        int idx = base + i;
        int c = (idx < V_) ? counts[idx] : 0;
        local[i] = s;
        s += c;
    }
    psum[t] = s;
    __syncthreads();
    for (int off = 1; off < 256; off <<= 1) {
        int v = (t >= off) ? psum[t - off] : 0;
        __syncthreads();
        psum[t] += v;
        __syncthreads();
    }
    int excl = (t == 0) ? 0 : psum[t - 1];
#pragma unroll
    for (int i = 0; i < 40; ++i) {
        int idx = base + i;
        if (idx < V_) {
            int rp = excl + local[i];
            row_ptr[idx] = rp;
            cursor[idx] = rp;
        }
    }
    if (t == 255) row_ptr[V_] = psum[255];
}

// ---------------------------------------------------------------------------
// 3) scatter edges into dst-sorted buckets; also pre-sort edge_attr for all
//    8 batches into bucket order: EAs[p][b]
// ---------------------------------------------------------------------------
__global__ __launch_bounds__(256) void bucket_kernel(
    const int* __restrict__ EI, const float* __restrict__ EA,
    int* __restrict__ cursor, int* __restrict__ ssrc,
    float* __restrict__ EAs)
{
    int e = blockIdx.x * 256 + threadIdx.x;
    if (e < E_) {
        int src = EI[2 * e];
        int dst = EI[2 * e + 1];
        int p = atomicAdd(&cursor[dst], 1);
        ssrc[p] = src;
        float4 v0, v1;
        v0.x = EA[0 * E_ + e]; v0.y = EA[1 * E_ + e];
        v0.z = EA[2 * E_ + e]; v0.w = EA[3 * E_ + e];
        v1.x = EA[4 * E_ + e]; v1.y = EA[5 * E_ + e];
        v1.z = EA[6 * E_ + e]; v1.w = EA[7 * E_ + e];
        *(float4*)(EAs + (size_t)p * 8) = v0;
        *(float4*)(EAs + (size_t)p * 8 + 4) = v1;
    }
}

// ---------------------------------------------------------------------------
// 4) gather-reduce, f16, 4 edges per load-step, batch-per-XCD swizzled.
//    Quarter-wave q (16 lanes x 16B) covers one full 256B row of edge j+q:
//    one shfl + one dwordx4 load serve 4 edges. Cross-quarter combine at end.
// ---------------------------------------------------------------------------
__global__ __launch_bounds__(256) void gather_kernel(
    const _Float16* __restrict__ Xh, const float* __restrict__ EAs,
    const int* __restrict__ row_ptr, const int* __restrict__ ssrc,
    _Float16* __restrict__ Ah, float* __restrict__ S)
{
    const int b = blockIdx.x & 7;             // batch -> XCD
    const int dblk = blockIdx.x >> 3;         // 0..2499
    const int w = threadIdx.x >> 6;           // 4 waves/block
    const int lane = threadIdx.x & 63;
    const int q = lane >> 4;                  // which edge of the 4-pack
    const int sl = lane & 15;                 // 16B segment: halves sl*8..sl*8+7
    const int d = dblk * 4 + w;
    const int wid = b * V_ + d;
    const int k0 = row_ptr[d];
    const int k1 = row_ptr[d + 1];
    const _Float16* Xb = Xh + (size_t)b * V_ * DIN + sl * 8;
    half2_t a0 = (half2_t)0, a1 = (half2_t)0, a2 = (half2_t)0, a3 = (half2_t)0;
    float ea = 0.0f;
    for (int kb = k0; kb < k1; kb += 64) {
        int cnt = min(64, k1 - kb);
        int msrc = 0;
        if (lane < cnt) {
            msrc = ssrc[kb + lane];
            ea += EAs[(size_t)(kb + lane) * 8 + b];
        }
        int j = 0;
        for (; j + 16 <= cnt; j += 16) {
#pragma unroll
            for (int u = 0; u < 4; ++u) {
                int s = __shfl(msrc, j + u * 4 + q);
                uint4 v = *(const uint4*)(Xb + (size_t)s * DIN);
                a0 += i2h(v.x); a1 += i2h(v.y); a2 += i2h(v.z); a3 += i2h(v.w);
            }
        }
        for (; j + 4 <= cnt; j += 4) {
            int s = __shfl(msrc, j + q);
            uint4 v = *(const uint4*)(Xb + (size_t)s * DIN);
            a0 += i2h(v.x); a1 += i2h(v.y); a2 += i2h(v.z); a3 += i2h(v.w);
        }
        if (j < cnt) {
            int s = __shfl(msrc, j + q);
            if (j + q < cnt) {
                uint4 v = *(const uint4*)(Xb + (size_t)s * DIN);
                a0 += i2h(v.x); a1 += i2h(v.y); a2 += i2h(v.z); a3 += i2h(v.w);
            }
        }
    }
    // combine the 4 edge-offset quarters (lanes differing by 32, then 16)
#pragma unroll
    for (int off = 32; off >= 16; off >>= 1) {
        a0 += i2h(__shfl_down(h2i(a0), off));
        a1 += i2h(__shfl_down(h2i(a1), off));
        a2 += i2h(__shfl_down(h2i(a2), off));
        a3 += i2h(__shfl_down(h2i(a3), off));
    }
    // edge_attr wave reduction
    for (int off = 32; off; off >>= 1) ea += __shfl_down(ea, off);
    if (lane == 0) S[wid] = ea;
    if (lane < 16) {
        uint4 o;
        o.x = h2i(a0); o.y = h2i(a1); o.z = h2i(a2); o.w = h2i(a3);
        *(uint4*)(Ah + (size_t)wid * DIN + sl * 8) = o;
    }
}

// ---------------------------------------------------------------------------
// GEMM body shared by both paths (device inline): computes acc[2][8] with
// bias + S*w_edge applied, and the block's 256 stat-partials in cs/css.
// ---------------------------------------------------------------------------
__device__ __forceinline__ void gemm_body(
    const _Float16* __restrict__ Xh, const _Float16* __restrict__ Ah,
    const _Float16* __restrict__ Wpk, const float* __restrict__ S,
    const float* __restrict__ bself, const float* __restrict__ wedge,
    int bid, int t, f32x4 (&acc)[2][8], float* cs, float* css)
{
    const int wave = t >> 6;
    const int lane = t & 63;
    const int quad = lane >> 4;
    const int ln = lane & 15;
    const int rowbase = bid * 128 + wave * 32;
    const int m0 = rowbase + ln;
    const int m1 = rowbase + 16 + ln;

    if (t < 128) { cs[t] = 0.0f; css[t] = 0.0f; }

#pragma unroll
    for (int mt = 0; mt < 2; ++mt)
#pragma unroll
        for (int nt = 0; nt < 8; ++nt) acc[mt][nt] = (f32x4){0.f, 0.f, 0.f, 0.f};

    const _Float16* X0 = Xh + (size_t)m0 * DIN + quad * 8;
    const _Float16* X1 = Xh + (size_t)m1 * DIN + quad * 8;
    const _Float16* A0 = Ah + (size_t)m0 * DIN + quad * 8;
    const _Float16* A1 = Ah + (size_t)m1 * DIN + quad * 8;
    const _Float16* Wl = Wpk + lane * 8;

#pragma unroll
    for (int ks = 0; ks < 8; ++ks) {
        half8_t af0, af1;
        if (ks < 4) {
            af0 = *(const half8_t*)(X0 + ks * 32);
            af1 = *(const half8_t*)(X1 + ks * 32);
        } else {
            af0 = *(const half8_t*)(A0 + (ks - 4) * 32);
            af1 = *(const half8_t*)(A1 + (ks - 4) * 32);
        }
#pragma unroll
        for (int nt = 0; nt < 8; ++nt) {
            half8_t bfr = *(const half8_t*)(Wl + (size_t)(ks * 8 + nt) * 512);
            acc[0][nt] = __builtin_amdgcn_mfma_f32_16x16x32_f16(af0, bfr, acc[0][nt], 0, 0, 0);
            acc[1][nt] = __builtin_amdgcn_mfma_f32_16x16x32_f16(af1, bfr, acc[1][nt], 0, 0, 0);
        }
    }

    float bs[8], we[8];
#pragma unroll
    for (int nt = 0; nt < 8; ++nt) {
        int c = nt * 16 + ln;
        bs[nt] = bself[c];
        we[nt] = wedge[c];
    }
    float psum[8], psq[8];
#pragma unroll
    for (int nt = 0; nt < 8; ++nt) { psum[nt] = 0.0f; psq[nt] = 0.0f; }

#pragma unroll
    for (int mt = 0; mt < 2; ++mt) {
        const int rbase = rowbase + mt * 16 + quad * 4;
        float sv[4];
#pragma unroll
        for (int r = 0; r < 4; ++r) sv[r] = S[rbase + r];
#pragma unroll
        for (int nt = 0; nt < 8; ++nt) {
#pragma unroll
            for (int r = 0; r < 4; ++r) {
                float h = acc[mt][nt][r] + bs[nt] + sv[r] * we[nt];
                acc[mt][nt][r] = h;
                psum[nt] += h;
                psq[nt] += h * h;
            }
        }
    }
#pragma unroll
    for (int nt = 0; nt < 8; ++nt) {
        psum[nt] += __shfl_down(psum[nt], 32);
        psum[nt] += __shfl_down(psum[nt], 16);
        psq[nt] += __shfl_down(psq[nt], 32);
        psq[nt] += __shfl_down(psq[nt], 16);
    }
    __syncthreads();
    if (lane < 16) {
#pragma unroll
        for (int nt = 0; nt < 8; ++nt) {
            atomicAdd(&cs[nt * 16 + ln], psum[nt]);
            atomicAdd(&css[nt * 16 + ln], psq[nt]);
        }
    }
    __syncthreads();
}

// ---------------------------------------------------------------------------
// 5a) Cooperative: GEMM -> partials -> grid.sync -> reduce -> grid.sync ->
//     normalize + ReLU from registers, single H write.
// ---------------------------------------------------------------------------
__global__ __launch_bounds__(256, 4) void gemm_norm_coop_kernel(
    const _Float16* __restrict__ Xh, const _Float16* __restrict__ Ah,
    const _Float16* __restrict__ Wpk, const float* __restrict__ S,
    const float* __restrict__ bself, const float* __restrict__ wedge,
    const float* __restrict__ gamma, const float* __restrict__ beta,
    float* __restrict__ H, float* __restrict__ Partials,
    float* __restrict__ gsum, float* __restrict__ gsumsq)
{
    __shared__ float cs[128];
    __shared__ float css[128];
    const int t = threadIdx.x;
    f32x4 acc[2][8];
    gemm_body(Xh, Ah, Wpk, S, bself, wedge, blockIdx.x, t, acc, cs, css);

    Partials[(size_t)blockIdx.x * 256 + t] = (t < 128) ? cs[t] : css[t - 128];
    __threadfence();
    cg::this_grid().sync();

    // blocks 0..255: wave 0 reduces slot c = blockIdx.x over 625 partials
    if (blockIdx.x < 256 && t < 64) {
        const int c = blockIdx.x;
        float a = 0.0f;
        for (int p = t; p < GEMM_BLOCKS; p += 64)
            a += Partials[(size_t)p * 256 + c];
        for (int off = 32; off; off >>= 1) a += __shfl_down(a, off);
        if (t == 0) {
            if (c < 128) gsum[c] = a;
            else gsumsq[c - 128] = a;
        }
        __threadfence();
    }
    cg::this_grid().sync();

    // normalize + relu, single store
    const int wave = t >> 6;
    const int lane = t & 63;
    const int quad = lane >> 4;
    const int ln = lane & 15;
    const int rowbase = blockIdx.x * 128 + wave * 32;
    float scl[8], shf[8];
#pragma unroll
    for (int nt = 0; nt < 8; ++nt) {
        int c = nt * 16 + ln;
        float gs = __hip_atomic_load(&gsum[c], __ATOMIC_RELAXED,
                                     __HIP_MEMORY_SCOPE_AGENT);
        float gq = __hip_atomic_load(&gsumsq[c], __ATOMIC_RELAXED,
                                     __HIP_MEMORY_SCOPE_AGENT);
        float mean = gs * NINV;
        float rstd = rsqrtf(gq * NINV - mean * mean + BN_EPS);
        scl[nt] = gamma[c] * rstd;
        shf[nt] = beta[c] - mean * scl[nt];
    }
#pragma unroll
    for (int mt = 0; mt < 2; ++mt) {
        const int rbase = rowbase + mt * 16 + quad * 4;
#pragma unroll
        for (int r = 0; r < 4; ++r) {
            float* Hr = H + (size_t)(rbase + r) * DOUT + ln;
#pragma unroll
            for (int nt = 0; nt < 8; ++nt)
                Hr[nt * 16] = fmaxf(acc[mt][nt][r] * scl[nt] + shf[nt], 0.0f);
        }
    }
}

// ---------------------------------------------------------------------------
// 5b) Fallback: GEMM + H store + partials (R10 path)
// ---------------------------------------------------------------------------
__global__ __launch_bounds__(256) void mfma_gemm_kernel(
    const _Float16* __restrict__ Xh, const _Float16* __restrict__ Ah,
    const _Float16* __restrict__ Wpk, const float* __restrict__ S,
    const float* __restrict__ bself, const float* __restrict__ wedge,
    float* __restrict__ H, float* __restrict__ Partials)
{
    __shared__ float cs[128];
    __shared__ float css[128];
    const int t = threadIdx.x;
    f32x4 acc[2][8];
    gemm_body(Xh, Ah, Wpk, S, bself, wedge, blockIdx.x, t, acc, cs, css);

    const int wave = t >> 6;
    const int lane = t & 63;
    const int quad = lane >> 4;
    const int ln = lane & 15;
    const int rowbase = blockIdx.x * 128 + wave * 32;
#pragma unroll
    for (int mt = 0; mt < 2; ++mt) {
        const int rbase = rowbase + mt * 16 + quad * 4;
#pragma unroll
        for (int r = 0; r < 4; ++r) {
            float* Hr = H + (size_t)(rbase + r) * DOUT + ln;
#pragma unroll
            for (int nt = 0; nt < 8; ++nt)
                Hr[nt * 16] = acc[mt][nt][r];
        }
    }
    Partials[(size_t)blockIdx.x * 256 + t] = (t < 128) ? cs[t] : css[t - 128];
}

// ---------------------------------------------------------------------------
// 6) fallback: reduce partials -> gsum/gsumsq
// ---------------------------------------------------------------------------
__global__ __launch_bounds__(64) void reduce_stats_kernel(
    const float* __restrict__ Partials, float* __restrict__ gsum,
    float* __restrict__ gsumsq)
{
    const int c = blockIdx.x;       // 0..255
    const int t = threadIdx.x;      // 0..63
    float acc = 0.0f;
    for (int p = t; p < GEMM_BLOCKS; p += 64)
        acc += Partials[(size_t)p * 256 + c];
    for (int off = 32; off; off >>= 1) acc += __shfl_down(acc, off);
    if (t == 0) {
        if (c < 128) gsum[c] = acc;
        else gsumsq[c - 128] = acc;
    }
}

// ---------------------------------------------------------------------------
// 7) fallback: normalize + ReLU in place
// ---------------------------------------------------------------------------
__global__ __launch_bounds__(256) void norm_relu_kernel(
    float* __restrict__ H, const float* __restrict__ gsum,
    const float* __restrict__ gsumsq, const float* __restrict__ gamma,
    const float* __restrict__ beta)
{
    int idx = blockIdx.x * 256 + threadIdx.x;   // over M_*128/4 float4s
    int o4 = (idx & 31) * 4;
    float4 s = *(const float4*)(gsum + o4);
    float4 q = *(const float4*)(gsumsq + o4);
    float4 g = *(const float4*)(gamma + o4);
    float4 bt = *(const float4*)(beta + o4);
    float4 sc, sh;
    {
        float m0 = s.x * NINV, m1 = s.y * NINV, m2 = s.z * NINV, m3 = s.w * NINV;
        float r0 = rsqrtf(q.x * NINV - m0 * m0 + BN_EPS);
        float r1 = rsqrtf(q.y * NINV - m1 * m1 + BN_EPS);
        float r2 = rsqrtf(q.z * NINV - m2 * m2 + BN_EPS);
        float r3 = rsqrtf(q.w * NINV - m3 * m3 + BN_EPS);
        sc.x = g.x * r0; sc.y = g.y * r1; sc.z = g.z * r2; sc.w = g.w * r3;
        sh.x = bt.x - m0 * sc.x; sh.y = bt.y - m1 * sc.y;
        sh.z = bt.z - m2 * sc.z; sh.w = bt.w - m3 * sc.w;
    }
    float4 h = ((const float4*)H)[idx];
    h.x = fmaxf(h.x * sc.x + sh.x, 0.0f);
    h.y = fmaxf(h.y * sc.y + sh.y, 0.0f);
    h.z = fmaxf(h.z * sc.z + sh.z, 0.0f);
    h.w = fmaxf(h.w * sc.w + sh.w, 0.0f);
    ((float4*)H)[idx] = h;
}

// ---------------------------------------------------------------------------
extern "C" void kernel_launch(void* const* d_in, const int* in_sizes, int n_in,
                              void* d_out, int out_size, void* d_ws, size_t ws_size,
                              hipStream_t stream)
{
    const float* X      = (const float*)d_in[0];
    const float* EA     = (const float*)d_in[1];
    const float* Wnode  = (const float*)d_in[2];
    const float* Wedge  = (const float*)d_in[3];
    const float* Wself  = (const float*)d_in[4];
    const float* bself  = (const float*)d_in[5];
    const float* gamma  = (const float*)d_in[6];
    const float* beta   = (const float*)d_in[7];
    const int*   EI     = (const int*)d_in[8];

    int*   wsI    = (int*)d_ws;
    float* wsF    = (float*)d_ws;
    int*   counts = wsI + WS_COUNTS;
    float* gsum   = wsF + WS_SUM;
    float* gsumsq = wsF + WS_SUMSQ;
    int*   rowptr = wsI + WS_ROWPTR;
    int*   cursor = wsI + WS_CURSOR;
    int*   ssrc   = wsI + WS_SSRC;
    float* EAs    = wsF + WS_EAS;
    float* S      = wsF + WS_S;
    _Float16* Wpk = (_Float16*)(wsI + WS_WPK);
    _Float16* Xh  = (_Float16*)(wsI + WS_XH);
    _Float16* Ah  = (_Float16*)(wsI + WS_AH);
    float* Partials = wsF + WS_PART;
    float* H      = (float*)d_out;

    hipMemsetAsync(d_ws, 0, (size_t)WS_ZERO_UNITS * 4, stream);

    // fused prep: xcvt (10000 blocks) + W pack (16) + hist (625)
    prep_kernel<<<10641, 256, 0, stream>>>(X, Xh, Wself, Wnode, Wpk, EI, counts);
    scan_kernel<<<1, 256, 0, stream>>>(counts, rowptr, cursor);
    bucket_kernel<<<(E_ + 255) / 256, 256, 0, stream>>>(EI, EA, cursor, ssrc, EAs);

    // gather-reduce -> Ah, S  (batch-per-XCD swizzle, 4 edges/load-step)
    gather_kernel<<<M_ / 4, 256, 0, stream>>>(Xh, EAs, rowptr, ssrc, Ah, S);

    // GEMM + stats + norm: cooperative single-pass if co-residency certain
    int blocksPerCU = 0;
    hipError_t qerr = hipOccupancyMaxActiveBlocksPerMultiprocessor(
        &blocksPerCU, gemm_norm_coop_kernel, 256, 0);
    bool coop = (qerr == hipSuccess) && (blocksPerCU * 256 >= GEMM_BLOCKS);
    if (coop) {
        void* args[] = { (void*)&Xh, (void*)&Ah, (void*)&Wpk, (void*)&S,
                         (void*)&bself, (void*)&Wedge, (void*)&gamma,
                         (void*)&beta, (void*)&H, (void*)&Partials,
                         (void*)&gsum, (void*)&gsumsq };
        hipError_t lerr = hipLaunchCooperativeKernel(
            (void*)gemm_norm_coop_kernel, dim3(GEMM_BLOCKS), dim3(256),
            args, 0, stream);
        if (lerr == hipSuccess) return;
        // fall through to safe path on launch failure
    }
    mfma_gemm_kernel<<<GEMM_BLOCKS, 256, 0, stream>>>(Xh, Ah, Wpk, S, bself,
                                                      Wedge, H, Partials);
    reduce_stats_kernel<<<256, 64, 0, stream>>>(Partials, gsum, gsumsq);
    norm_relu_kernel<<<(M_ * DOUT / 4) / 256, 256, 0, stream>>>(H, gsum, gsumsq,
                                                                gamma, beta);
}